// Round 1
// baseline (550.205 us; speedup 1.0000x reference)
//
#include <hip/hip_runtime.h>
#include <hip/hip_bf16.h>
#include <math.h>

// DCNv2 CrossNet on MI355X: 3 fused cross-layer kernels using bf16 MFMA
// (16x16x32), fp32 accumulate, fp32 residual chain.
//
// Shapes: x[32768,512]; Vs[3,4,64,512]; Cs[3,4,64,64]; Us[3,4,512,64];
//         bias[3,512]; gate_w[512,4].

#define CROSS   3
#define ENUM    4
#define LR      64
#define ELD     256     // ENUM*LR
#define DIM     512
#define BATCH   32768
#define BT      32      // batch rows per block
#define NTHR    256     // 4 waves

#define XL_W    520     // 512 + 8 pad (keeps 16B align, rotates banks)
#define Y_W     264     // 256 + 8 pad
#define GT_W    516     // 512 + 4 pad (fp32) -> conflict-free 4-expert reads

typedef __bf16 bf16x8 __attribute__((ext_vector_type(8)));
typedef float  f32x4  __attribute__((ext_vector_type(4)));
typedef unsigned short us4 __attribute__((ext_vector_type(4)));

__device__ __forceinline__ unsigned short f2bf(float f) {
    return __builtin_bit_cast(unsigned short, (__bf16)f);
}

// ---------------------------------------------------------------------------
// Weight swizzle pre-passes: fp32 [N][K] row-major -> bf16 MFMA-B fragment
// order: frag[nt][ks][lane][8] with n = nt*16 + (lane&15),
//                               k = ks*32 + (lane>>4)*8 + j.
// Makes the main-loop B loads one coalesced 16B/lane global_load_dwordx4.
// ---------------------------------------------------------------------------
__global__ __launch_bounds__(64) void swz_v(const float* __restrict__ Vs,
                                            unsigned short* __restrict__ Vf) {
    int blk = blockIdx.x;                 // CROSS * (16 nt * 16 ks)
    int i = blk >> 8, t = blk & 255;
    int nt = t >> 4, ks = t & 15;
    int lane = threadIdx.x;
    int n  = nt * 16 + (lane & 15);
    int k0 = ks * 32 + (lane >> 4) * 8;
    const float* src = Vs + (size_t)i * ELD * DIM + (size_t)n * DIM + k0;
    unsigned short* dst = Vf + (size_t)i * ELD * DIM
                        + ((size_t)(nt * 16 + ks) * 64 + lane) * 8;
    #pragma unroll
    for (int j = 0; j < 8; ++j) dst[j] = f2bf(src[j]);
}

// U'[n=d][k=e*64+l] = Us[i][e][d][l]  (N=512, K=256)
__global__ __launch_bounds__(64) void swz_u(const float* __restrict__ Us,
                                            unsigned short* __restrict__ Uf) {
    int blk = blockIdx.x;                 // CROSS * (32 nt * 8 ks)
    int i = blk >> 8, t = blk & 255;
    int nt = t >> 3, ks = t & 7;
    int lane = threadIdx.x;
    int n  = nt * 16 + (lane & 15);       // d
    int k0 = ks * 32 + (lane >> 4) * 8;   // e*64 + l
    int e = k0 >> 6, l0 = k0 & 63;
    const float* src = Us + (size_t)i * ENUM * DIM * LR
                     + (size_t)e * DIM * LR + (size_t)n * LR + l0;
    unsigned short* dst = Uf + (size_t)i * DIM * ELD
                        + ((size_t)(nt * 8 + ks) * 64 + lane) * 8;
    #pragma unroll
    for (int j = 0; j < 8; ++j) dst[j] = f2bf(src[j]);
}

// C per (layer, expert): [n=l][k] = Cs[i][e][n][k]  (N=64, K=64)
__global__ __launch_bounds__(64) void swz_c(const float* __restrict__ Cs,
                                            unsigned short* __restrict__ Cf) {
    int blk = blockIdx.x;                 // CROSS*ENUM * (4 nt * 2 ks)
    int i = blk >> 5, rest = blk & 31;
    int e = rest >> 3, t = rest & 7;
    int nt = t >> 1, ks = t & 1;
    int lane = threadIdx.x;
    int n  = nt * 16 + (lane & 15);
    int k0 = ks * 32 + (lane >> 4) * 8;
    const float* src = Cs + (((size_t)(i * ENUM + e) * LR + n) * LR) + k0;
    unsigned short* dst = Cf + (size_t)i * ENUM * LR * LR
                        + ((size_t)((e * 4 + nt) * 2 + ks) * 64 + lane) * 8;
    #pragma unroll
    for (int j = 0; j < 8; ++j) dst[j] = f2bf(src[j]);
}

// ---------------------------------------------------------------------------
// One fused cross layer. Block: 32 batch rows, 256 threads (4 waves).
// Wave w owns output columns [w*64, w*64+64) of GEMM1 (Y), expert w of
// GEMM2, and output columns [w*128, w*128+128) of GEMM3.
// ---------------------------------------------------------------------------
__global__ __launch_bounds__(NTHR) void cross_layer(
    const float* __restrict__ xl_in,   // [B, D] fp32, current x_l
    const float* __restrict__ x0,      // [B, D] fp32, original x
    float* __restrict__ x_out,         // [B, D] fp32 (may alias xl_in)
    const unsigned short* __restrict__ Vf,   // [16][16][64][8] bf16 frags
    const unsigned short* __restrict__ Cf,   // [4][4][2][64][8]
    const unsigned short* __restrict__ Uf,   // [32][8][64][8]
    const float* __restrict__ gate_w,  // [D, E] fp32
    const float* __restrict__ bias)    // [D] fp32 (this layer)
{
    __shared__ unsigned short xl_s[BT * XL_W];   // x_l tile, bf16
    __shared__ unsigned short y_s[BT * Y_W];     // Y then (aliased) z
    __shared__ float gate_t[ENUM * GT_W];        // gate transposed fp32
    __shared__ float g_s[BT * ENUM];             // gating scores

    const int tid  = threadIdx.x;
    const int wave = tid >> 6, lane = tid & 63;
    const int quad = lane >> 4, nl = lane & 15;
    const int row0 = blockIdx.x * BT;

    // ---- Phase 0: stage x_l -> LDS (bf16) and gate_w^T -> LDS (fp32)
    #pragma unroll
    for (int it = 0; it < 16; ++it) {
        int f4 = tid + it * NTHR;          // 0..4095 float4s
        int r = f4 >> 7, c4 = f4 & 127;
        float4 v = *reinterpret_cast<const float4*>(
            xl_in + (size_t)(row0 + r) * DIM + c4 * 4);
        us4 p;
        p[0] = f2bf(v.x); p[1] = f2bf(v.y); p[2] = f2bf(v.z); p[3] = f2bf(v.w);
        *reinterpret_cast<us4*>(&xl_s[r * XL_W + c4 * 4]) = p;
    }
    #pragma unroll
    for (int it = 0; it < 8; ++it) {
        int idx = tid + it * NTHR;         // 0..2047
        int d = idx >> 2, e = idx & 3;
        gate_t[e * GT_W + d] = gate_w[idx];
    }
    __syncthreads();

    // ---- Phase 1a: gate scores g[b,e] (threads 0..127, VALU)
    if (tid < 128) {
        int r = tid >> 2, e = tid & 3;
        float acc = 0.f;
        #pragma unroll 4
        for (int d0 = 0; d0 < DIM; d0 += 8) {
            bf16x8 xv = *reinterpret_cast<const bf16x8*>(&xl_s[r * XL_W + d0]);
            const f32x4* gp =
                reinterpret_cast<const f32x4*>(&gate_t[e * GT_W + d0]);
            f32x4 g0 = gp[0], g1 = gp[1];
            acc += (float)xv[0] * g0[0] + (float)xv[1] * g0[1]
                 + (float)xv[2] * g0[2] + (float)xv[3] * g0[3]
                 + (float)xv[4] * g1[0] + (float)xv[5] * g1[1]
                 + (float)xv[6] * g1[2] + (float)xv[7] * g1[3];
        }
        g_s[r * ENUM + e] = acc;
    }

    // ---- Phase 1b: GEMM1  Y = tanh(xl @ V^T), wave cols [wave*64, +64)
    f32x4 acc1[2][4];
    #pragma unroll
    for (int mt = 0; mt < 2; ++mt)
        #pragma unroll
        for (int nt = 0; nt < 4; ++nt) acc1[mt][nt] = (f32x4)0.f;

    #pragma unroll 4
    for (int ks = 0; ks < 16; ++ks) {
        bf16x8 a0 = *reinterpret_cast<const bf16x8*>(
            &xl_s[(nl) * XL_W + ks * 32 + quad * 8]);
        bf16x8 a1 = *reinterpret_cast<const bf16x8*>(
            &xl_s[(16 + nl) * XL_W + ks * 32 + quad * 8]);
        #pragma unroll
        for (int nt = 0; nt < 4; ++nt) {
            bf16x8 b = *reinterpret_cast<const bf16x8*>(
                &Vf[((size_t)((wave * 4 + nt) * 16 + ks) * 64 + lane) * 8]);
            acc1[0][nt] = __builtin_amdgcn_mfma_f32_16x16x32_bf16(
                a0, b, acc1[0][nt], 0, 0, 0);
            acc1[1][nt] = __builtin_amdgcn_mfma_f32_16x16x32_bf16(
                a1, b, acc1[1][nt], 0, 0, 0);
        }
    }
    // D layout: row = quad*4 + r (+16*mt), col = nt*16 + nl (+64*wave)
    #pragma unroll
    for (int mt = 0; mt < 2; ++mt)
        #pragma unroll
        for (int r = 0; r < 4; ++r) {
            int row = mt * 16 + quad * 4 + r;
            #pragma unroll
            for (int nt = 0; nt < 4; ++nt) {
                int col = wave * 64 + nt * 16 + nl;
                y_s[row * Y_W + col] = f2bf(tanhf(acc1[mt][nt][r]));
            }
        }
    __syncthreads();

    // ---- Phase 2: GEMM2 per expert (wave = expert e), K=64
    //      c = tanh(Y_e @ C_e^T);  z = g[:,e] * c  written back in place
    //      (wave e reads/writes only columns [e*64, e*64+64) of y_s).
    f32x4 acc2[2][4];
    #pragma unroll
    for (int mt = 0; mt < 2; ++mt)
        #pragma unroll
        for (int nt = 0; nt < 4; ++nt) acc2[mt][nt] = (f32x4)0.f;

    #pragma unroll
    for (int ks = 0; ks < 2; ++ks) {
        bf16x8 a0 = *reinterpret_cast<const bf16x8*>(
            &y_s[(nl) * Y_W + wave * 64 + ks * 32 + quad * 8]);
        bf16x8 a1 = *reinterpret_cast<const bf16x8*>(
            &y_s[(16 + nl) * Y_W + wave * 64 + ks * 32 + quad * 8]);
        #pragma unroll
        for (int nt = 0; nt < 4; ++nt) {
            bf16x8 b = *reinterpret_cast<const bf16x8*>(
                &Cf[((size_t)((wave * 4 + nt) * 2 + ks) * 64 + lane) * 8]);
            acc2[0][nt] = __builtin_amdgcn_mfma_f32_16x16x32_bf16(
                a0, b, acc2[0][nt], 0, 0, 0);
            acc2[1][nt] = __builtin_amdgcn_mfma_f32_16x16x32_bf16(
                a1, b, acc2[1][nt], 0, 0, 0);
        }
    }
    #pragma unroll
    for (int mt = 0; mt < 2; ++mt)
        #pragma unroll
        for (int r = 0; r < 4; ++r) {
            int row = mt * 16 + quad * 4 + r;
            float gv = g_s[row * ENUM + wave];
            #pragma unroll
            for (int nt = 0; nt < 4; ++nt) {
                int col = wave * 64 + nt * 16 + nl;
                y_s[row * Y_W + col] = f2bf(tanhf(acc2[mt][nt][r]) * gv);
            }
        }
    __syncthreads();

    // ---- Phase 3: GEMM3  core = z @ U'^T, wave cols [wave*128, +128), K=256
    f32x4 acc3[2][8];
    #pragma unroll
    for (int mt = 0; mt < 2; ++mt)
        #pragma unroll
        for (int nt = 0; nt < 8; ++nt) acc3[mt][nt] = (f32x4)0.f;

    #pragma unroll 2
    for (int ks = 0; ks < 8; ++ks) {
        bf16x8 a0 = *reinterpret_cast<const bf16x8*>(
            &y_s[(nl) * Y_W + ks * 32 + quad * 8]);
        bf16x8 a1 = *reinterpret_cast<const bf16x8*>(
            &y_s[(16 + nl) * Y_W + ks * 32 + quad * 8]);
        #pragma unroll
        for (int nt = 0; nt < 8; ++nt) {
            bf16x8 b = *reinterpret_cast<const bf16x8*>(
                &Uf[((size_t)((wave * 8 + nt) * 8 + ks) * 64 + lane) * 8]);
            acc3[0][nt] = __builtin_amdgcn_mfma_f32_16x16x32_bf16(
                a0, b, acc3[0][nt], 0, 0, 0);
            acc3[1][nt] = __builtin_amdgcn_mfma_f32_16x16x32_bf16(
                a1, b, acc3[1][nt], 0, 0, 0);
        }
    }

    // ---- Epilogue: out = x_l + x0 * (core + bias*G), fp32 residual chain
    float Gv[2][4];
    #pragma unroll
    for (int mt = 0; mt < 2; ++mt)
        #pragma unroll
        for (int r = 0; r < 4; ++r) {
            int row = mt * 16 + quad * 4 + r;
            Gv[mt][r] = g_s[row * ENUM + 0] + g_s[row * ENUM + 1]
                      + g_s[row * ENUM + 2] + g_s[row * ENUM + 3];
        }
    #pragma unroll
    for (int nt = 0; nt < 8; ++nt) {
        int col = (wave * 8 + nt) * 16 + nl;
        float bc = bias[col];
        #pragma unroll
        for (int mt = 0; mt < 2; ++mt)
            #pragma unroll
            for (int r = 0; r < 4; ++r) {
                int row = mt * 16 + quad * 4 + r;
                size_t g = (size_t)(row0 + row) * DIM + col;
                float res = xl_in[g]
                          + x0[g] * (acc3[mt][nt][r] + bc * Gv[mt][r]);
                x_out[g] = res;
            }
    }
}

// ---------------------------------------------------------------------------
extern "C" void kernel_launch(void* const* d_in, const int* in_sizes, int n_in,
                              void* d_out, int out_size, void* d_ws,
                              size_t ws_size, hipStream_t stream) {
    const float* x      = (const float*)d_in[0];
    const float* Vs     = (const float*)d_in[1];
    const float* Cs     = (const float*)d_in[2];
    const float* Us     = (const float*)d_in[3];
    const float* bias   = (const float*)d_in[4];
    const float* gate_w = (const float*)d_in[5];
    float* out = (float*)d_out;

    char* ws = (char*)d_ws;
    float* xf = (float*)ws;                                   // [B,D] fp32 ping
    unsigned short* Vf = (unsigned short*)(ws + (size_t)BATCH * DIM * 4);
    unsigned short* Uf = Vf + (size_t)CROSS * ELD * DIM;
    unsigned short* Cf = Uf + (size_t)CROSS * DIM * ELD;

    swz_v<<<CROSS * 256, 64, 0, stream>>>(Vs, Vf);
    swz_u<<<CROSS * 256, 64, 0, stream>>>(Us, Uf);
    swz_c<<<CROSS * ENUM * 8, 64, 0, stream>>>(Cs, Cf);

    dim3 grid(BATCH / BT);
    // layer 0: x -> xf
    cross_layer<<<grid, NTHR, 0, stream>>>(x, x, xf,
        Vf, Cf, Uf, gate_w, bias);
    // layer 1: xf -> xf (in place; rows are block-exclusive)
    cross_layer<<<grid, NTHR, 0, stream>>>(xf, x, xf,
        Vf + (size_t)ELD * DIM, Cf + (size_t)ENUM * LR * LR,
        Uf + (size_t)DIM * ELD, gate_w, bias + DIM);
    // layer 2: xf -> out
    cross_layer<<<grid, NTHR, 0, stream>>>(xf, x, out,
        Vf + 2 * (size_t)ELD * DIM, Cf + 2 * (size_t)ENUM * LR * LR,
        Uf + 2 * (size_t)DIM * ELD, gate_w, bias + 2 * DIM);
}